// Round 2
// baseline (928.099 us; speedup 1.0000x reference)
//
#include <hip/hip_runtime.h>
#include <math.h>

// B=16384, N=64, D=64. One batch per 256-thread block (4 waves share the
// 16.6KB rel tile). Wave w owns j-slice [16w,16w+16) -> h[16] in VGPRs.
// LDS ~17.8KB/block -> 8 blocks/CU * 4 waves = 32 waves/CU (100% occupancy),
// vs round-1's 8 waves/CU (22%). rel_s stride 65: column reads (n+k)%32 ->
// 2-way bank aliasing = free.
#define BATCH 16384
#define NN 64
#define DD 64
#define RS 65   // rel_s row stride (floats)

__global__ __launch_bounds__(256, 8)
void aggregator_kernel(const float* __restrict__ self_v,   // [B,64]
                       const float* __restrict__ nv,       // [B,64,64]
                       const float* __restrict__ rel,      // [B,64,64]
                       const float* __restrict__ ue,       // [B,64]
                       const float* __restrict__ W1,       // [128,64]
                       const float* __restrict__ b1,       // [64]
                       const float* __restrict__ w2,       // [64]
                       const float* __restrict__ b2,       // [1]
                       float* __restrict__ out)            // [B,128]
{
    const int b    = blockIdx.x;
    const int t    = threadIdx.x;   // 0..255
    const int lane = t & 63;
    const int w    = t >> 6;        // wave 0..3

    __shared__ float rel_s[NN * RS];   // 16640 B, [n][k] stride 65
    __shared__ float red[4 * 64];      // cross-wave reduction buffer (reused 3x)
    __shared__ float u1_s[DD];
    __shared__ float wbuf[NN];

    const float*  relb = rel + (size_t)b * (NN * DD);
    const float4* rel4 = (const float4*)relb;

    // ---- stage rel: 1024 float4s, thread t takes f = t,t+256,t+512,t+768 ----
    // writes: bank = (65n + 4kq + i)%32 = (n + 4kq + i)%32 -> 2-way = free
    #pragma unroll
    for (int c = 0; c < 4; ++c) {
        int f = t + 256 * c;
        float4 v = rel4[f];
        int n = f >> 4, kq = f & 15;
        float* dst = &rel_s[n * RS + kq * 4];
        dst[0] = v.x; dst[1] = v.y; dst[2] = v.z; dst[3] = v.w;
    }

    // ---- u1 partials: thread (j=lane, k-quarter=w) does 16 FMAs ----
    {
        const float* ueb = ue + (size_t)b * DD + w * 16;   // wave-uniform -> s_load
        const float* W1a = W1 + (w * 16) * DD + lane;      // coalesced
        float acc = 0.0f;
        #pragma unroll
        for (int k = 0; k < 16; ++k) acc = fmaf(ueb[k], W1a[k * DD], acc);
        red[t] = acc;
    }
    __syncthreads();

    if (t < 64)
        u1_s[t] = b1[t] + red[t] + red[64 + t] + red[128 + t] + red[192 + t];
    __syncthreads();

    // ---- hidden: thread (n=lane, j in [16w,16w+16)) ----
    const int j0 = w * 16;
    float h[16];
    #pragma unroll
    for (int jj = 0; jj < 16; ++jj) h[jj] = u1_s[j0 + jj];  // uniform -> broadcast

    const float* __restrict__ rrow = &rel_s[lane * RS];
    const float* __restrict__ W1b  = W1 + DD * DD + j0;
    #pragma unroll 8
    for (int k = 0; k < DD; ++k) {
        float x = rrow[k];                         // bank (n+k)%32: conflict-free
        const float* __restrict__ row = W1b + k * DD;   // wave-uniform -> s_load
        #pragma unroll
        for (int jj = 0; jj < 16; ++jj) h[jj] = fmaf(x, row[jj], h[jj]);
    }

    // ---- decay partial: relu(h) . w2 slice ----
    {
        const float* w2s = w2 + j0;                // wave-uniform -> s_load
        float p = 0.0f;
        #pragma unroll
        for (int jj = 0; jj < 16; ++jj) p = fmaf(fmaxf(h[jj], 0.0f), w2s[jj], p);
        red[t] = p;
    }
    __syncthreads();

    // ---- wave 0: finish decay, sigmoid, softmax over 64 neighbors ----
    if (t < 64) {
        float d = b2[0] + red[t] + red[64 + t] + red[128 + t] + red[192 + t];
        float dec = 1.0f / (1.0f + __expf(-d));
        float m = dec;
        #pragma unroll
        for (int off = 32; off > 0; off >>= 1) m = fmaxf(m, __shfl_xor(m, off, 64));
        float e = __expf(dec - m);
        float s = e;
        #pragma unroll
        for (int off = 32; off > 0; off >>= 1) s += __shfl_xor(s, off, 64);
        wbuf[t] = e / s;
    }
    __syncthreads();   // wave0 done reading red before agg overwrites it

    // ---- agg partial: thread (j=lane, n in [16w,16w+16)), nv coalesced ----
    {
        const float* nvb = nv + (size_t)b * (NN * DD) + (w * 16) * DD + lane;
        float ap = 0.0f;
        #pragma unroll
        for (int i = 0; i < 16; ++i)
            ap = fmaf(wbuf[w * 16 + i], nvb[i * DD], ap);   // wbuf uniform bcast
        red[t] = ap;
    }
    __syncthreads();

    // ---- output: [self | agg] ----
    if (t < 64) {
        out[(size_t)b * (2 * DD) + t] = self_v[(size_t)b * DD + t];
    } else if (t < 128) {
        int j = t - 64;
        out[(size_t)b * (2 * DD) + DD + j] =
            red[j] + red[64 + j] + red[128 + j] + red[192 + j];
    }
}

extern "C" void kernel_launch(void* const* d_in, const int* in_sizes, int n_in,
                              void* d_out, int out_size, void* d_ws, size_t ws_size,
                              hipStream_t stream) {
    const float* self_v = (const float*)d_in[0];
    const float* nv     = (const float*)d_in[1];
    const float* rel    = (const float*)d_in[2];
    const float* ue     = (const float*)d_in[3];
    const float* W1     = (const float*)d_in[4];
    const float* b1     = (const float*)d_in[5];
    const float* w2     = (const float*)d_in[6];
    const float* b2     = (const float*)d_in[7];
    float* out = (float*)d_out;

    aggregator_kernel<<<dim3(BATCH), dim3(256), 0, stream>>>(
        self_v, nv, rel, ue, W1, b1, w2, b2, out);
}